// Round 2
// baseline (455.756 us; speedup 1.0000x reference)
//
#include <hip/hip_runtime.h>

typedef unsigned short u16;
typedef __attribute__((ext_vector_type(4))) float f32x4;
typedef __attribute__((ext_vector_type(8))) unsigned short u16x8;
typedef __attribute__((ext_vector_type(4))) unsigned short u16x4;
typedef __attribute__((ext_vector_type(8))) short s16x8;

__device__ __forceinline__ u16 f2bf(float f) {
    unsigned u = __float_as_uint(f);
    u += 0x7FFFu + ((u >> 16) & 1u);   // RNE
    return (u16)(u >> 16);
}
__device__ __forceinline__ float bf2f(u16 h) {
    return __uint_as_float(((unsigned)h) << 16);
}

// ---------------------------------------------------------------------------
// K1: W (1024x1024 fp32, k-major) -> Wt (1024x1024 bf16, n-major = W^T)
// ---------------------------------------------------------------------------
__global__ void wtrans_k(const float* __restrict__ W, u16* __restrict__ Wt) {
    __shared__ float tile[32][33];
    const int k0 = blockIdx.x << 5, n0 = blockIdx.y << 5;
    const int tx = threadIdx.x & 31, ty = threadIdx.x >> 5;  // ty in [0,8)
#pragma unroll
    for (int r = 0; r < 32; r += 8)
        tile[ty + r][tx] = W[(size_t)(k0 + ty + r) * 1024 + n0 + tx];
    __syncthreads();
#pragma unroll
    for (int r = 0; r < 32; r += 8)
        Wt[(size_t)(n0 + ty + r) * 1024 + k0 + tx] = f2bf(tile[tx][ty + r]);
}

// ---------------------------------------------------------------------------
// K2: GEMM  U[r=b*512+s][col=i*64+d] = sum_k X[s][b][k] * Wt[col][k]  (bf16 out)
// 128x128 tile, BK=32, 4 waves (2x2), mfma_f32_16x16x32_bf16, double-buffered.
// A is fp32 in HBM -> reg-stage + convert; B (Wt) is bf16 -> reg-stage copy.
// ---------------------------------------------------------------------------
__global__ void gemm_k(const float* __restrict__ X, const u16* __restrict__ Wt,
                       u16* __restrict__ U) {
    __shared__ u16 lds[16384];  // [2][128*32] A | [2][128*32] B ; reused as C 128x128
    const int tid = threadIdx.x;
    const int lane = tid & 63, wave = tid >> 6;
    const int bid = blockIdx.x;
    const int tm = bid >> 3, tn = bid & 7;     // tn fastest: A-panel reuse
    const int r0 = tm << 7, c0 = tn << 7;
    const int wm = wave >> 1, wn = wave & 1;   // 2x2 waves of 64x64

    const int arow = tid >> 1, ahalf = tid & 1;
    const int s_ = (r0 + arow) & 511, b_ = (r0 + arow) >> 9;  // fold (S,B)->(B,S)
    const float* asrc = X + ((size_t)s_ * 64 + b_) * 1024 + (ahalf << 4);
    const u16* bsrc = Wt + ((size_t)(c0 + arow)) * 1024 + (ahalf << 4);
    const int sOff = (arow << 5) + (ahalf << 4);

    const int lrow = lane & 15, lk = (lane >> 4) << 3;

    f32x4 acc[4][4] = {};

    // prologue: stage k-tile 0 into buf 0
    {
        const f32x4* ap = (const f32x4*)asrc;
        f32x4 A0 = ap[0], A1 = ap[1], A2 = ap[2], A3 = ap[3];
        const u16x8* bp = (const u16x8*)bsrc;
        u16x8 B0 = bp[0], B1 = bp[1];
        u16x8 pa0, pa1;
#pragma unroll
        for (int j = 0; j < 4; ++j) {
            pa0[j] = f2bf(A0[j]); pa0[4 + j] = f2bf(A1[j]);
            pa1[j] = f2bf(A2[j]); pa1[4 + j] = f2bf(A3[j]);
        }
        *(u16x8*)&lds[sOff] = pa0;       *(u16x8*)&lds[sOff + 8] = pa1;
        *(u16x8*)&lds[8192 + sOff] = B0; *(u16x8*)&lds[8192 + sOff + 8] = B1;
    }
    __syncthreads();

#pragma unroll 2
    for (int kt = 0; kt < 32; ++kt) {
        const int cur = kt & 1, nxt = cur ^ 1;
        f32x4 A0, A1, A2, A3;
        u16x8 B0, B1;
        const bool has_next = (kt < 31);
        if (has_next) {  // issue next-tile loads early; use-distance spans the MFMAs
            const int k0 = (kt + 1) << 5;
            const f32x4* ap = (const f32x4*)(asrc + k0);
            A0 = ap[0]; A1 = ap[1]; A2 = ap[2]; A3 = ap[3];
            const u16x8* bp = (const u16x8*)(bsrc + k0);
            B0 = bp[0]; B1 = bp[1];
        }
        const u16* sA = lds + cur * 4096;
        const u16* sB = lds + 8192 + cur * 4096;
        s16x8 af[4], bfr[4];
#pragma unroll
        for (int m = 0; m < 4; ++m)
            af[m] = *(const s16x8*)&sA[((wm << 6) + (m << 4) + lrow) * 32 + lk];
#pragma unroll
        for (int n = 0; n < 4; ++n)
            bfr[n] = *(const s16x8*)&sB[((wn << 6) + (n << 4) + lrow) * 32 + lk];
#pragma unroll
        for (int m = 0; m < 4; ++m)
#pragma unroll
            for (int n = 0; n < 4; ++n)
                acc[m][n] = __builtin_amdgcn_mfma_f32_16x16x32_bf16(af[m], bfr[n], acc[m][n], 0, 0, 0);
        if (has_next) {
            u16x8 pa0, pa1;
#pragma unroll
            for (int j = 0; j < 4; ++j) {
                pa0[j] = f2bf(A0[j]); pa0[4 + j] = f2bf(A1[j]);
                pa1[j] = f2bf(A2[j]); pa1[4 + j] = f2bf(A3[j]);
            }
            u16* dA = lds + nxt * 4096;
            u16* dB = lds + 8192 + nxt * 4096;
            *(u16x8*)&dA[sOff] = pa0; *(u16x8*)&dA[sOff + 8] = pa1;
            *(u16x8*)&dB[sOff] = B0;  *(u16x8*)&dB[sOff + 8] = B1;
        }
        __syncthreads();
    }

    // epilogue: repack through LDS for coalesced bf16 stores
    u16* sC = lds;  // 128x128 u16 = 32 KB (all staging done)
#pragma unroll
    for (int m = 0; m < 4; ++m)
#pragma unroll
        for (int n = 0; n < 4; ++n)
#pragma unroll
            for (int j = 0; j < 4; ++j) {
                const int row = (wm << 6) + (m << 4) + ((lane >> 4) << 2) + j;
                const int col = (wn << 6) + (n << 4) + (lane & 15);
                sC[(row << 7) + col] = f2bf(acc[m][n][j]);
            }
    __syncthreads();
    const int orow = tid >> 1, ocol = (tid & 1) << 6;
    u16* gdst = U + ((size_t)(r0 + orow) << 10) + c0 + ocol;
    const u16* sp = sC + (orow << 7) + ocol;
#pragma unroll
    for (int q = 0; q < 8; ++q)
        *(u16x8*)(gdst + (q << 3)) = *(const u16x8*)(sp + (q << 3));
}

// ---------------------------------------------------------------------------
// K3: column sums  W0[b,i,d] += sum_s u[b,s,i,d]   (c uniform; squash is
// scale-invariant so the 1/16 is unnecessary)
// ---------------------------------------------------------------------------
__global__ void colsum_k(const u16* __restrict__ U, float* __restrict__ W0) {
    const int b = blockIdx.x, ch = blockIdx.y;
    const int t = threadIdx.x;
    const u16* base = U + (((size_t)b * 512 + ch * 64) << 10) + (t << 2);
    float a0 = 0, a1 = 0, a2 = 0, a3 = 0;
#pragma unroll 8
    for (int r = 0; r < 64; ++r) {
        u16x4 u4 = *(const u16x4*)(base + ((size_t)r << 10));
        a0 += bf2f(u4[0]); a1 += bf2f(u4[1]); a2 += bf2f(u4[2]); a3 += bf2f(u4[3]);
    }
    float* w = W0 + (b << 10) + (t << 2);
    atomicAdd(w, a0); atomicAdd(w + 1, a1); atomicAdd(w + 2, a2); atomicAdd(w + 3, a3);
}

// ---------------------------------------------------------------------------
// K4: squash — v[g,:] = w[g,:] / sqrt(sum_d w^2 + 1e-7), 1024 groups of 64
// ---------------------------------------------------------------------------
__global__ void squash_k(const float* __restrict__ Win, float* __restrict__ Vout) {
    const int g = (blockIdx.x << 2) + (threadIdx.x >> 6);
    const int lane = threadIdx.x & 63;
    float x = Win[((size_t)g << 6) + lane];
    float s = x * x;
#pragma unroll
    for (int d = 1; d < 64; d <<= 1) s += __shfl_xor(s, d);
    Vout[((size_t)g << 6) + lane] = x / sqrtf(s + 1e-7f);
}

// ---------------------------------------------------------------------------
// K5: fused routing pass t:  b_t = b_{t-1} + v_{t-1}·u ; c = softmax_i(b_t) ;
//     w_t += c·u    — ONE read of u per iteration.
// grid (16 s-chunks, 64 batches), 256 threads; wave handles 8 s; lane l owns
// cols [16l,16l+16) of the 1024-wide u row => capsule i = l>>2, d-block l&3.
// ---------------------------------------------------------------------------
__global__ void route_pass(const u16* __restrict__ U, const float* __restrict__ V,
                           float* __restrict__ Bbuf, float* __restrict__ Wout,
                           const int hasB, const int writeB) {
    const int tid = threadIdx.x;
    const int wave = tid >> 6, lane = tid & 63;
    const int b = blockIdx.y;
    const int grp = lane >> 2, sub = lane & 3;
    __shared__ float wlds[1024];
    for (int q = tid; q < 1024; q += 256) wlds[q] = 0.f;
    float v[16];
    const float* vp = V + (size_t)((b << 4) + grp) * 64 + (sub << 4);
#pragma unroll
    for (int j = 0; j < 16; ++j) v[j] = vp[j];
    float wacc[16] = {};
    const int s0 = (blockIdx.x << 5) + (wave << 3);
    __syncthreads();
#pragma unroll 2
    for (int ss = 0; ss < 8; ++ss) {
        const int s = s0 + ss;
        const size_t rbase = (size_t)(b << 9) + s;
        const u16x8* up = (const u16x8*)(U + (rbase << 10) + (lane << 4));
        u16x8 u0 = up[0], u1 = up[1];
        float uf[16];
#pragma unroll
        for (int j = 0; j < 8; ++j) { uf[j] = bf2f(u0[j]); uf[8 + j] = bf2f(u1[j]); }
        float p = 0.f;
#pragma unroll
        for (int j = 0; j < 16; ++j) p = fmaf(uf[j], v[j], p);
        p += __shfl_xor(p, 1);
        p += __shfl_xor(p, 2);          // 4-lane group now holds d_i = v_i · u[i,s]
        float bn = p;
        if (hasB) bn += Bbuf[(rbase << 4) + grp];
        float mx = bn;                  // softmax over the 16 capsules (butterfly)
#pragma unroll
        for (int d = 4; d < 64; d <<= 1) mx = fmaxf(mx, __shfl_xor(mx, d));
        float e = __expf(bn - mx);
        float sm = e;
#pragma unroll
        for (int d = 4; d < 64; d <<= 1) sm += __shfl_xor(sm, d);
        const float c = e / sm;
        if (writeB && sub == 0) Bbuf[(rbase << 4) + grp] = bn;
#pragma unroll
        for (int j = 0; j < 16; ++j) wacc[j] = fmaf(c, uf[j], wacc[j]);
    }
#pragma unroll
    for (int j = 0; j < 16; ++j) atomicAdd(&wlds[(lane << 4) + j], wacc[j]);
    __syncthreads();
    for (int q = tid; q < 1024; q += 256) atomicAdd(&Wout[(size_t)(b << 10) + q], wlds[q]);
}

// ---------------------------------------------------------------------------
// workspace layout (bytes):
//   [0, 64M)          u   bf16 32768x1024
//   [64M, 66M)        Wt  bf16 1024x1024
//   [66M.., +1M)      w0..w3  fp32 4x65536
//   [.. , +768K)      v0..v2  fp32 3x65536
//   [.. , +2M)        b   fp32 64x512x16
// ---------------------------------------------------------------------------
#define WS_U   ((size_t)0)
#define WS_WT  ((size_t)67108864)
#define WS_W   ((size_t)69206016)
#define WS_V   ((size_t)70254592)
#define WS_B   ((size_t)71041024)

extern "C" void kernel_launch(void* const* d_in, const int* in_sizes, int n_in,
                              void* d_out, int out_size, void* d_ws, size_t ws_size,
                              hipStream_t stream) {
    (void)in_sizes; (void)n_in; (void)out_size; (void)ws_size;
    const float* x = (const float*)d_in[0];
    const float* W = (const float*)d_in[1];
    float* out = (float*)d_out;
    char* ws = (char*)d_ws;
    u16* U = (u16*)(ws + WS_U);
    u16* Wt = (u16*)(ws + WS_WT);
    float* wbuf = (float*)(ws + WS_W);
    float* vbuf = (float*)(ws + WS_V);
    float* bbuf = (float*)(ws + WS_B);

    hipMemsetAsync(wbuf, 0, 4 * 65536 * sizeof(float), stream);
    wtrans_k<<<dim3(32, 32), 256, 0, stream>>>(W, Wt);
    gemm_k<<<2048, 256, 0, stream>>>(x, Wt, U);
    colsum_k<<<dim3(64, 8), 256, 0, stream>>>(U, wbuf);                      // w0
    squash_k<<<256, 256, 0, stream>>>(wbuf, vbuf);                           // v0
    route_pass<<<dim3(16, 64), 256, 0, stream>>>(U, vbuf, bbuf, wbuf + 65536, 0, 1);
    squash_k<<<256, 256, 0, stream>>>(wbuf + 65536, vbuf + 65536);           // v1
    route_pass<<<dim3(16, 64), 256, 0, stream>>>(U, vbuf + 65536, bbuf, wbuf + 2 * 65536, 1, 1);
    squash_k<<<256, 256, 0, stream>>>(wbuf + 2 * 65536, vbuf + 2 * 65536);   // v2
    route_pass<<<dim3(16, 64), 256, 0, stream>>>(U, vbuf + 2 * 65536, bbuf, wbuf + 3 * 65536, 1, 0);
    squash_k<<<256, 256, 0, stream>>>(wbuf + 3 * 65536, out);                // outputs
}

// Round 3
// 406.994 us; speedup vs baseline: 1.1198x; 1.1198x over previous
//
#include <hip/hip_runtime.h>

typedef unsigned short u16;
typedef __attribute__((ext_vector_type(4))) float f32x4;
typedef __attribute__((ext_vector_type(8))) unsigned short u16x8;
typedef __attribute__((ext_vector_type(8))) short s16x8;

__device__ __forceinline__ u16 f2bf(float f) {
    unsigned u = __float_as_uint(f);
    u += 0x7FFFu + ((u >> 16) & 1u);   // RNE
    return (u16)(u >> 16);
}
__device__ __forceinline__ float bf2f(u16 h) {
    return __uint_as_float(((unsigned)h) << 16);
}
__device__ __forceinline__ void gload_lds16(const void* g, void* l) {
    __builtin_amdgcn_global_load_lds(
        (const __attribute__((address_space(1))) unsigned int*)g,
        (__attribute__((address_space(3))) unsigned int*)l, 16, 0, 0);
}

// ---------------------------------------------------------------------------
// K1: W (1024x1024 fp32, k-major) -> Wt (1024x1024 bf16, n-major = W^T)
// ---------------------------------------------------------------------------
__global__ void wtrans_k(const float* __restrict__ W, u16* __restrict__ Wt) {
    __shared__ float tile[32][33];
    const int k0 = blockIdx.x << 5, n0 = blockIdx.y << 5;
    const int tx = threadIdx.x & 31, ty = threadIdx.x >> 5;
#pragma unroll
    for (int r = 0; r < 32; r += 8)
        tile[ty + r][tx] = W[(size_t)(k0 + ty + r) * 1024 + n0 + tx];
    __syncthreads();
#pragma unroll
    for (int r = 0; r < 32; r += 8)
        Wt[(size_t)(n0 + ty + r) * 1024 + k0 + tx] = f2bf(tile[tx][ty + r]);
}

// ---------------------------------------------------------------------------
// K2: GEMM U[b*512+s][i*64+d] = sum_k X[s][b][k] * Wt[col][k], bf16 out.
// 128x128 tile, BK=32, 2x2 waves, double-buffered.
// XCD-swizzle: blocks sharing an A-panel (tn group of 8) run consecutively
// on ONE XCD -> A panel stays L2-resident (fixes 4.2x HBM over-fetch).
// B staged via global_load_lds (16B); A reg-staged fp32->bf16 (needs cvt).
// Epilogue: C store + fused column-sum (c uniform in routing iter 0).
// ---------------------------------------------------------------------------
__global__ void gemm_k(const float* __restrict__ X, const u16* __restrict__ Wt,
                       u16* __restrict__ U, float* __restrict__ W0) {
    __shared__ u16 lds[16384];  // [2][4096] A | [2][4096] B ; reused as C 128x128
    const int tid = threadIdx.x;
    const int lane = tid & 63, wave = tid >> 6;
    // XCD-aware bijective swizzle (2048 blocks, 8 XCDs, 256 per XCD)
    const int swz = (int)blockIdx.x;
    const int orig = ((swz & 7) << 8) + (swz >> 3);
    const int tm = orig >> 3, tn = orig & 7;
    const int r0 = tm << 7, c0 = tn << 7;
    const int wm = wave >> 1, wn = wave & 1;

    const int arow = tid >> 1, ahalf = tid & 1;
    const int s_ = (r0 + arow) & 511, b_ = (r0 + arow) >> 9;  // fold (S,B)->(B,S)
    const float* asrc = X + ((size_t)s_ * 64 + b_) * 1024 + (ahalf << 4);
    const int sOff = (arow << 5) + (ahalf << 4);

    // B gload_lds: thread t, chunk q in {0,1}: buffer byte t*16 + q*4096
    //   -> row (t>>2)+q*64, k-chunk (t&3)*8 of the [128][32] tile
    const u16* bg0 = Wt + ((size_t)(c0 + (tid >> 2)) << 10) + ((tid & 3) << 3);
    const u16* bg1 = bg0 + (size_t)(64 << 10);
    const int bOff = (wave << 9);  // u16 elems; +q*2048

    const int lrow = lane & 15, lk = (lane >> 4) << 3;
    f32x4 acc[4][4] = {};

    // prologue: stage k-tile 0 into buf 0
    {
        const f32x4* ap = (const f32x4*)asrc;
        f32x4 A0 = ap[0], A1 = ap[1], A2 = ap[2], A3 = ap[3];
        gload_lds16(bg0, &lds[8192 + bOff]);
        gload_lds16(bg1, &lds[8192 + bOff + 2048]);
        u16x8 pa0, pa1;
#pragma unroll
        for (int j = 0; j < 4; ++j) {
            pa0[j] = f2bf(A0[j]); pa0[4 + j] = f2bf(A1[j]);
            pa1[j] = f2bf(A2[j]); pa1[4 + j] = f2bf(A3[j]);
        }
        *(u16x8*)&lds[sOff] = pa0; *(u16x8*)&lds[sOff + 8] = pa1;
    }
    __syncthreads();

#pragma unroll 2
    for (int kt = 0; kt < 32; ++kt) {
        const int cur = kt & 1, nxt = cur ^ 1;
        f32x4 A0, A1, A2, A3;
        const bool has_next = (kt < 31);
        if (has_next) {
            const int k0e = (kt + 1) << 5;
            const f32x4* ap = (const f32x4*)(asrc + k0e);
            A0 = ap[0]; A1 = ap[1]; A2 = ap[2]; A3 = ap[3];
            gload_lds16(bg0 + k0e, &lds[8192 + nxt * 4096 + bOff]);
            gload_lds16(bg1 + k0e, &lds[8192 + nxt * 4096 + bOff + 2048]);
        }
        const u16* sA = lds + cur * 4096;
        const u16* sB = lds + 8192 + cur * 4096;
        s16x8 af[4], bfr[4];
#pragma unroll
        for (int m = 0; m < 4; ++m)
            af[m] = *(const s16x8*)&sA[((wm << 6) + (m << 4) + lrow) * 32 + lk];
#pragma unroll
        for (int n = 0; n < 4; ++n)
            bfr[n] = *(const s16x8*)&sB[((wn << 6) + (n << 4) + lrow) * 32 + lk];
#pragma unroll
        for (int m = 0; m < 4; ++m)
#pragma unroll
            for (int n = 0; n < 4; ++n)
                acc[m][n] = __builtin_amdgcn_mfma_f32_16x16x32_bf16(af[m], bfr[n], acc[m][n], 0, 0, 0);
        if (has_next) {
            u16x8 pa0, pa1;
#pragma unroll
            for (int j = 0; j < 4; ++j) {
                pa0[j] = f2bf(A0[j]); pa0[4 + j] = f2bf(A1[j]);
                pa1[j] = f2bf(A2[j]); pa1[4 + j] = f2bf(A3[j]);
            }
            u16* dA = lds + nxt * 4096;
            *(u16x8*)&dA[sOff] = pa0; *(u16x8*)&dA[sOff + 8] = pa1;
        }
        __syncthreads();
    }

    // epilogue 1: repack C through LDS
    u16* sC = lds;
#pragma unroll
    for (int m = 0; m < 4; ++m)
#pragma unroll
        for (int n = 0; n < 4; ++n)
#pragma unroll
            for (int j = 0; j < 4; ++j) {
                const int row = (wm << 6) + (m << 4) + ((lane >> 4) << 2) + j;
                const int col = (wn << 6) + (n << 4) + (lane & 15);
                sC[(row << 7) + col] = f2bf(acc[m][n][j]);
            }
    // epilogue 2: fused column-sum from acc (fp32, pre-rounding)
    {
        const int bb = tm >> 2;  // tile lies in one batch (128 | 512)
#pragma unroll
        for (int n = 0; n < 4; ++n) {
            float p = 0.f;
#pragma unroll
            for (int m = 0; m < 4; ++m)
#pragma unroll
                for (int j = 0; j < 4; ++j) p += acc[m][n][j];
            p += __shfl_xor(p, 16);
            p += __shfl_xor(p, 32);   // all 64 rows of this wave summed
            if (lane < 16)
                atomicAdd(&W0[(bb << 10) + c0 + (wn << 6) + (n << 4) + lane], p);
        }
    }
    __syncthreads();
    const int orow = tid >> 1, ocol = (tid & 1) << 6;
    u16* gdst = U + ((size_t)(r0 + orow) << 10) + c0 + ocol;
    const u16* sp = sC + (orow << 7) + ocol;
#pragma unroll
    for (int q = 0; q < 8; ++q)
        *(u16x8*)(gdst + (q << 3)) = *(const u16x8*)(sp + (q << 3));
}

// ---------------------------------------------------------------------------
// K4: squash — v[g,:] = w[g,:] / sqrt(sum_d w^2 + 1e-7), 1024 groups of 64
// ---------------------------------------------------------------------------
__global__ void squash_k(const float* __restrict__ Win, float* __restrict__ Vout) {
    const int g = (blockIdx.x << 2) + (threadIdx.x >> 6);
    const int lane = threadIdx.x & 63;
    float x = Win[((size_t)g << 6) + lane];
    float s = x * x;
#pragma unroll
    for (int d = 1; d < 64; d <<= 1) s += __shfl_xor(s, d);
    Vout[((size_t)g << 6) + lane] = x / sqrtf(s + 1e-7f);
}

// ---------------------------------------------------------------------------
// K5: fused routing pass:  b += v·u ; c = softmax_i(b) ; w += c·u
// grid (16,64), 256 thr; wave owns 8 s-rows; lane l owns cols [16l,16l+16).
// 4-row pipelined load batches for MLP; per-wave padded LDS slices (no LDS
// atomics, 8-way not 32-way conflicts); 1 global atomic per col per block.
// ---------------------------------------------------------------------------
__global__ void route_pass(const u16* __restrict__ U, const float* __restrict__ V,
                           float* __restrict__ Bbuf, float* __restrict__ Wout,
                           const int hasB, const int writeB) {
    const int tid = threadIdx.x;
    const int wave = tid >> 6, lane = tid & 63;
    const int b = blockIdx.y, bx = blockIdx.x;
    const int grp = lane >> 2, sub = lane & 3;
    __shared__ float wlds[4 * 64 * 20];  // padded stride 20 (16B-aligned rows)
    float v[16];
    const float* vp = V + (size_t)((b << 4) + grp) * 64 + (sub << 4);
#pragma unroll
    for (int j = 0; j < 16; ++j) v[j] = vp[j];
    float wacc[16] = {};
    const int s0 = (bx << 5) + (wave << 3);
    const size_t rbase0 = (size_t)(b << 9) + s0;
    const u16* ubase = U + (rbase0 << 10) + (lane << 4);

    u16x8 cv0[4], cv1[4], nv0[4], nv1[4];
#pragma unroll
    for (int r = 0; r < 4; ++r) {
        const u16x8* up = (const u16x8*)(ubase + ((size_t)r << 10));
        cv0[r] = up[0]; cv1[r] = up[1];
    }
#pragma unroll
    for (int half = 0; half < 2; ++half) {
        if (half == 0) {
#pragma unroll
            for (int r = 0; r < 4; ++r) {
                const u16x8* up = (const u16x8*)(ubase + ((size_t)(r + 4) << 10));
                nv0[r] = up[0]; nv1[r] = up[1];
            }
        }
#pragma unroll
        for (int r = 0; r < 4; ++r) {
            const int s = s0 + (half << 2) + r;
            const size_t rb = (size_t)(b << 9) + s;
            float uf[16];
#pragma unroll
            for (int j = 0; j < 8; ++j) { uf[j] = bf2f(cv0[r][j]); uf[8 + j] = bf2f(cv1[r][j]); }
            float p = 0.f;
#pragma unroll
            for (int j = 0; j < 16; ++j) p = fmaf(uf[j], v[j], p);
            p += __shfl_xor(p, 1);
            p += __shfl_xor(p, 2);      // 4-lane group holds d_i = v_i · u[i,s]
            float bn = p;
            if (hasB) bn += Bbuf[(rb << 4) + grp];
            float mx = bn;
#pragma unroll
            for (int d = 4; d < 64; d <<= 1) mx = fmaxf(mx, __shfl_xor(mx, d));
            float e = __expf(bn - mx);
            float sm = e;
#pragma unroll
            for (int d = 4; d < 64; d <<= 1) sm += __shfl_xor(sm, d);
            const float c = e / sm;
            if (writeB && sub == 0) Bbuf[(rb << 4) + grp] = bn;
#pragma unroll
            for (int j = 0; j < 16; ++j) wacc[j] = fmaf(c, uf[j], wacc[j]);
        }
        if (half == 0) {
#pragma unroll
            for (int r = 0; r < 4; ++r) { cv0[r] = nv0[r]; cv1[r] = nv1[r]; }
        }
    }
    // per-wave exclusive slice, padded stride 20 floats
    const int rowb = ((wave << 6) + lane) * 20;
#pragma unroll
    for (int j = 0; j < 16; ++j) wlds[rowb + j] = wacc[j];
    __syncthreads();
#pragma unroll
    for (int c = 0; c < 4; ++c) {
        const int q = tid + (c << 8);
        const int l = q >> 4, j = q & 15;
        float s = 0.f;
#pragma unroll
        for (int w = 0; w < 4; ++w) s += wlds[((w << 6) + l) * 20 + j];
        atomicAdd(&Wout[((size_t)b << 10) + q], s);
    }
}

// ---------------------------------------------------------------------------
// workspace layout (bytes) — identical footprint to the proven r2 layout:
//   [0, 64M)    U bf16 | [64M,66M) Wt | +1M w0..w3 | +768K v0..v2 | +2M b
// ---------------------------------------------------------------------------
#define WS_U   ((size_t)0)
#define WS_WT  ((size_t)67108864)
#define WS_W   ((size_t)69206016)
#define WS_V   ((size_t)70254592)
#define WS_B   ((size_t)71041024)

extern "C" void kernel_launch(void* const* d_in, const int* in_sizes, int n_in,
                              void* d_out, int out_size, void* d_ws, size_t ws_size,
                              hipStream_t stream) {
    (void)in_sizes; (void)n_in; (void)out_size; (void)ws_size;
    const float* x = (const float*)d_in[0];
    const float* W = (const float*)d_in[1];
    float* out = (float*)d_out;
    char* ws = (char*)d_ws;
    u16* U = (u16*)(ws + WS_U);
    u16* Wt = (u16*)(ws + WS_WT);
    float* wbuf = (float*)(ws + WS_W);
    float* vbuf = (float*)(ws + WS_V);
    float* bbuf = (float*)(ws + WS_B);

    hipMemsetAsync(wbuf, 0, 4 * 65536 * sizeof(float), stream);
    wtrans_k<<<dim3(32, 32), 256, 0, stream>>>(W, Wt);
    gemm_k<<<2048, 256, 0, stream>>>(x, Wt, U, wbuf);
    squash_k<<<256, 256, 0, stream>>>(wbuf, vbuf);                           // v0
    route_pass<<<dim3(16, 64), 256, 0, stream>>>(U, vbuf, bbuf, wbuf + 65536, 0, 1);
    squash_k<<<256, 256, 0, stream>>>(wbuf + 65536, vbuf + 65536);           // v1
    route_pass<<<dim3(16, 64), 256, 0, stream>>>(U, vbuf + 65536, bbuf, wbuf + 2 * 65536, 1, 1);
    squash_k<<<256, 256, 0, stream>>>(wbuf + 2 * 65536, vbuf + 2 * 65536);   // v2
    route_pass<<<dim3(16, 64), 256, 0, stream>>>(U, vbuf + 2 * 65536, bbuf, wbuf + 3 * 65536, 1, 0);
    squash_k<<<256, 256, 0, stream>>>(wbuf + 3 * 65536, out);                // outputs
}

// Round 5
// 394.148 us; speedup vs baseline: 1.1563x; 1.0326x over previous
//
#include <hip/hip_runtime.h>

typedef unsigned short u16;
typedef __attribute__((ext_vector_type(4))) float f32x4;
typedef __attribute__((ext_vector_type(8))) unsigned short u16x8;
typedef __attribute__((ext_vector_type(8))) short s16x8;

__device__ __forceinline__ u16 f2bf(float f) {
    unsigned u = __float_as_uint(f);
    u += 0x7FFFu + ((u >> 16) & 1u);   // RNE
    return (u16)(u >> 16);
}
__device__ __forceinline__ float bf2f(u16 h) {
    return __uint_as_float(((unsigned)h) << 16);
}
__device__ __forceinline__ void gload_lds16(const void* g, void* l) {
    __builtin_amdgcn_global_load_lds(
        (const __attribute__((address_space(1))) unsigned int*)g,
        (__attribute__((address_space(3))) unsigned int*)l, 16, 0, 0);
}

// ---------------------------------------------------------------------------
// K0: X (S,B,H) fp32 -> Xb (B,S,H) bf16. Row permutation only; reads and
// writes both coalesced (rows are 1024 contiguous elements).
// ---------------------------------------------------------------------------
__global__ void xcvt_k(const float* __restrict__ X, u16* __restrict__ Xb) {
    const int t = (int)(blockIdx.x * 256 + threadIdx.x);
    const int orow = t >> 7;              // out row = b*512+s, 128 thr/row
    const int col = (t & 127) << 3;
    const int b = orow >> 9, s = orow & 511;
    const float* src = X + (((size_t)s << 6) + b) * 1024 + col;
    f32x4 x0 = *(const f32x4*)src;
    f32x4 x1 = *(const f32x4*)(src + 4);
    u16x8 o;
#pragma unroll
    for (int j = 0; j < 4; ++j) { o[j] = f2bf(x0[j]); o[4 + j] = f2bf(x1[j]); }
    *(u16x8*)(Xb + ((size_t)orow << 10) + col) = o;
}

// ---------------------------------------------------------------------------
// K1: W (1024x1024 fp32, k-major) -> Wt (1024x1024 bf16, n-major = W^T)
// ---------------------------------------------------------------------------
__global__ void wtrans_k(const float* __restrict__ W, u16* __restrict__ Wt) {
    __shared__ float tile[32][33];
    const int k0 = blockIdx.x << 5, n0 = blockIdx.y << 5;
    const int tx = threadIdx.x & 31, ty = threadIdx.x >> 5;
#pragma unroll
    for (int r = 0; r < 32; r += 8)
        tile[ty + r][tx] = W[(size_t)(k0 + ty + r) * 1024 + n0 + tx];
    __syncthreads();
#pragma unroll
    for (int r = 0; r < 32; r += 8)
        Wt[(size_t)(n0 + ty + r) * 1024 + k0 + tx] = f2bf(tile[tx][ty + r]);
}

// ---------------------------------------------------------------------------
// K2: GEMM U[r][c] = sum_k Xb[r][k] * Wt[c][k], bf16 out. Pure m97 structure:
// 128x128 tile, BK=32, 2x2 waves, A AND B staged via global_load_lds (16B),
// double-buffered, XCD-bijective swizzle. Epilogue: C store + fused colsum.
// ---------------------------------------------------------------------------
__global__ void gemm_k(const u16* __restrict__ Xb, const u16* __restrict__ Wt,
                       u16* __restrict__ U, float* __restrict__ W0) {
    __shared__ u16 lds[16384];  // A dbuf [2][4096] @0 | B dbuf [2][4096] @8192
    const int tid = threadIdx.x;
    const int lane = tid & 63, wave = tid >> 6;
    const int swz = (int)blockIdx.x;                 // 2048 blocks, 8 XCDs
    const int orig = ((swz & 7) << 8) + (swz >> 3);  // bijective: 256/XCD
    const int tm = orig >> 3, tn = orig & 7;
    const int r0 = tm << 7, c0 = tn << 7;
    const int wm = wave >> 1, wn = wave & 1;

    // gload: thread t, chunk q: tile row q*64+(t>>2), k-chunk (t&3)*8
    const u16* ag0 = Xb + ((size_t)(r0 + (tid >> 2)) << 10) + ((tid & 3) << 3);
    const u16* ag1 = ag0 + ((size_t)64 << 10);
    const u16* bg0 = Wt + ((size_t)(c0 + (tid >> 2)) << 10) + ((tid & 3) << 3);
    const u16* bg1 = bg0 + ((size_t)64 << 10);
    const int sOff = wave << 9;  // LDS dest (u16 elems): wave-uniform, lane-linear

    const int lrow = lane & 15, lk = (lane >> 4) << 3;
    f32x4 acc[4][4] = {};

    // prologue: k-tile 0 -> buf 0
    gload_lds16(ag0, &lds[sOff]);
    gload_lds16(ag1, &lds[sOff + 2048]);
    gload_lds16(bg0, &lds[8192 + sOff]);
    gload_lds16(bg1, &lds[8192 + sOff + 2048]);
    __syncthreads();

#pragma unroll 2
    for (int kt = 0; kt < 32; ++kt) {
        const int cur = kt & 1, nxt = cur ^ 1;
        if (kt < 31) {
            const int ke = (kt + 1) << 5;
            gload_lds16(ag0 + ke, &lds[nxt * 4096 + sOff]);
            gload_lds16(ag1 + ke, &lds[nxt * 4096 + sOff + 2048]);
            gload_lds16(bg0 + ke, &lds[8192 + nxt * 4096 + sOff]);
            gload_lds16(bg1 + ke, &lds[8192 + nxt * 4096 + sOff + 2048]);
        }
        const u16* sA = lds + cur * 4096;
        const u16* sB = lds + 8192 + cur * 4096;
        s16x8 af[4], bfr[4];
#pragma unroll
        for (int m = 0; m < 4; ++m)
            af[m] = *(const s16x8*)&sA[((wm << 6) + (m << 4) + lrow) * 32 + lk];
#pragma unroll
        for (int n = 0; n < 4; ++n)
            bfr[n] = *(const s16x8*)&sB[((wn << 6) + (n << 4) + lrow) * 32 + lk];
#pragma unroll
        for (int m = 0; m < 4; ++m)
#pragma unroll
            for (int n = 0; n < 4; ++n)
                acc[m][n] = __builtin_amdgcn_mfma_f32_16x16x32_bf16(af[m], bfr[n], acc[m][n], 0, 0, 0);
        __syncthreads();
    }

    // epilogue 1: repack C through LDS (32 KB reuse; loop's final barrier done)
    u16* sC = lds;
#pragma unroll
    for (int m = 0; m < 4; ++m)
#pragma unroll
        for (int n = 0; n < 4; ++n)
#pragma unroll
            for (int j = 0; j < 4; ++j) {
                const int row = (wm << 6) + (m << 4) + ((lane >> 4) << 2) + j;
                const int col = (wn << 6) + (n << 4) + (lane & 15);
                sC[(row << 7) + col] = f2bf(acc[m][n][j]);
            }
    // epilogue 2: fused column-sum from fp32 acc (iter-0 c is uniform)
    {
        const int bb = tm >> 2;  // tile lies within one batch (128 | 512)
#pragma unroll
        for (int n = 0; n < 4; ++n) {
            float p = 0.f;
#pragma unroll
            for (int m = 0; m < 4; ++m)
#pragma unroll
                for (int j = 0; j < 4; ++j) p += acc[m][n][j];
            p += __shfl_xor(p, 16);
            p += __shfl_xor(p, 32);
            if (lane < 16)
                atomicAdd(&W0[(bb << 10) + c0 + (wn << 6) + (n << 4) + lane], p);
        }
    }
    __syncthreads();
    const int orow = tid >> 1, ocol = (tid & 1) << 6;
    u16* gdst = U + ((size_t)(r0 + orow) << 10) + c0 + ocol;
    const u16* sp = sC + (orow << 7) + ocol;
#pragma unroll
    for (int q = 0; q < 8; ++q)
        *(u16x8*)(gdst + (q << 3)) = *(const u16x8*)(sp + (q << 3));
}

// ---------------------------------------------------------------------------
// K4: squash (single input) — v[g,:] = w[g,:] / sqrt(sum w^2 + 1e-7)
// ---------------------------------------------------------------------------
__global__ void squash_k(const float* __restrict__ Win, float* __restrict__ Vout) {
    const int g = (blockIdx.x << 2) + (threadIdx.x >> 6);
    const int lane = threadIdx.x & 63;
    float x = Win[((size_t)g << 6) + lane];
    float s = x * x;
#pragma unroll
    for (int d = 1; d < 64; d <<= 1) s += __shfl_xor(s, d);
    Vout[((size_t)g << 6) + lane] = x / sqrtf(s + 1e-7f);
}

// ---------------------------------------------------------------------------
// K4b: squash over 16 partial sums: w[b,i,d] = sum_part WP[part][b][i*64+d]
// ---------------------------------------------------------------------------
__global__ void squash16_k(const float* __restrict__ WP, float* __restrict__ Vout) {
    const int g = (blockIdx.x << 2) + (threadIdx.x >> 6);  // b*16+i
    const int lane = threadIdx.x & 63;
    const int b = g >> 4, i = g & 15;
    const float* p = WP + (((size_t)b) << 10) + (i << 6) + lane;
    float x = 0.f;
#pragma unroll
    for (int c = 0; c < 16; ++c) x += p[((size_t)c) << 16];  // part stride 64*1024
    float s = x * x;
#pragma unroll
    for (int d = 1; d < 64; d <<= 1) s += __shfl_xor(s, d);
    Vout[((size_t)g << 6) + lane] = x / sqrtf(s + 1e-7f);
}

// ---------------------------------------------------------------------------
// K5: fused routing pass:  b += v·u ; c = softmax_i(b) ; w += c·u
// grid (16,64); wave owns 8 s-rows; lane l owns cols [16l,16l+16).
// All 16 U-loads issued upfront (16 in flight). Softmax skips max-sub
// (|b| <= 24 << 88). Block partials -> plain stores into WP (no atomics).
// ---------------------------------------------------------------------------
__global__ void route_pass(const u16* __restrict__ U, const float* __restrict__ V,
                           float* __restrict__ Bbuf, float* __restrict__ WP,
                           const int hasB, const int writeB) {
    const int tid = threadIdx.x;
    const int wave = tid >> 6, lane = tid & 63;
    const int b = blockIdx.y, bx = blockIdx.x;
    const int grp = lane >> 2, sub = lane & 3;
    __shared__ float wlds[4 * 64 * 20];  // per-wave slices, stride 20
    float v[16];
    const float* vp = V + (size_t)((b << 4) + grp) * 64 + (sub << 4);
#pragma unroll
    for (int j = 0; j < 16; ++j) v[j] = vp[j];
    float wacc[16] = {};
    const int s0 = (bx << 5) + (wave << 3);
    const size_t rbase0 = (size_t)(b << 9) + s0;
    const u16* ubase = U + (rbase0 << 10) + (lane << 4);

    u16x8 rv[16];
#pragma unroll
    for (int r = 0; r < 8; ++r) {
        const u16x8* up = (const u16x8*)(ubase + ((size_t)r << 10));
        rv[2 * r] = up[0];
        rv[2 * r + 1] = up[1];
    }
#pragma unroll
    for (int r = 0; r < 8; ++r) {
        const size_t rb = rbase0 + r;
        float uf[16];
#pragma unroll
        for (int j = 0; j < 8; ++j) {
            uf[j] = bf2f(rv[2 * r][j]);
            uf[8 + j] = bf2f(rv[2 * r + 1][j]);
        }
        float p = 0.f;
#pragma unroll
        for (int j = 0; j < 16; ++j) p = fmaf(uf[j], v[j], p);
        p += __shfl_xor(p, 1);
        p += __shfl_xor(p, 2);          // 4-lane group holds d_i = v_i · u[i,s]
        float bn = p;
        if (hasB) bn += Bbuf[(rb << 4) + grp];
        float e = __expf(bn);           // |bn| <= ~24: no max-sub needed
        float sm = e;
#pragma unroll
        for (int d = 4; d < 64; d <<= 1) sm += __shfl_xor(sm, d);
        const float c = e * __builtin_amdgcn_rcpf(sm);
        if (writeB && sub == 0) Bbuf[(rb << 4) + grp] = bn;
#pragma unroll
        for (int j = 0; j < 16; ++j) wacc[j] = fmaf(c, uf[j], wacc[j]);
    }
    const int rowb = ((wave << 6) + lane) * 20;
#pragma unroll
    for (int j = 0; j < 16; ++j) wlds[rowb + j] = wacc[j];
    __syncthreads();
    float* wpdst = WP + (((size_t)(bx << 6) + b) << 10);
#pragma unroll
    for (int c = 0; c < 4; ++c) {
        const int q = tid + (c << 8);
        const int l = q >> 4, j = q & 15;
        float s = 0.f;
#pragma unroll
        for (int w = 0; w < 4; ++w) s += wlds[((w << 6) + l) * 20 + j];
        wpdst[q] = s;                    // plain store, no atomics
    }
}

// ---------------------------------------------------------------------------
// workspace (bytes):
//   [0,64M)      U bf16
//   [64M,128M)   Xb bf16 (GEMM phase) -- reused post-GEMM: WP 4M | Bbuf 2M
//   [128M,130M)  Wt bf16
//   +256K w0 | +3x256K v0..v2          total ~131.3 MB
// ---------------------------------------------------------------------------
#define WS_U   ((size_t)0)
#define WS_XB  ((size_t)67108864)
#define WS_WP  ((size_t)67108864)
#define WS_BB  ((size_t)71303168)
#define WS_WT  ((size_t)134217728)
#define WS_W0  ((size_t)136314880)
#define WS_V   ((size_t)136577024)

extern "C" void kernel_launch(void* const* d_in, const int* in_sizes, int n_in,
                              void* d_out, int out_size, void* d_ws, size_t ws_size,
                              hipStream_t stream) {
    (void)in_sizes; (void)n_in; (void)out_size; (void)ws_size;
    const float* x = (const float*)d_in[0];
    const float* W = (const float*)d_in[1];
    float* out = (float*)d_out;
    char* ws = (char*)d_ws;
    u16* U = (u16*)(ws + WS_U);
    u16* Xb = (u16*)(ws + WS_XB);
    u16* Wt = (u16*)(ws + WS_WT);
    float* w0 = (float*)(ws + WS_W0);
    float* v0 = (float*)(ws + WS_V);
    float* v1 = v0 + 65536;
    float* v2 = v1 + 65536;
    float* wp = (float*)(ws + WS_WP);
    float* bb = (float*)(ws + WS_BB);

    hipMemsetAsync(w0, 0, 65536 * sizeof(float), stream);
    wtrans_k<<<dim3(32, 32), 256, 0, stream>>>(W, Wt);
    xcvt_k<<<16384, 256, 0, stream>>>(x, Xb);
    gemm_k<<<2048, 256, 0, stream>>>(Xb, Wt, U, w0);
    squash_k<<<256, 256, 0, stream>>>(w0, v0);
    route_pass<<<dim3(16, 64), 256, 0, stream>>>(U, v0, bb, wp, 0, 1);
    squash16_k<<<256, 256, 0, stream>>>(wp, v1);
    route_pass<<<dim3(16, 64), 256, 0, stream>>>(U, v1, bb, wp, 1, 1);
    squash16_k<<<256, 256, 0, stream>>>(wp, v2);
    route_pass<<<dim3(16, 64), 256, 0, stream>>>(U, v2, bb, wp, 1, 0);
    squash16_k<<<256, 256, 0, stream>>>(wp, out);
}